// Round 7
// baseline (1628.220 us; speedup 1.0000x reference)
//
#include <hip/hip_runtime.h>
#include <stdint.h>

// Problem constants (from reference setup_inputs)
#define Bg    128
#define NPG   512
#define Cc    128
#define EPG   8192
#define Nn    (Bg*NPG)      // 65536
#define Ee    (Bg*EPG)      // 1048576
#define Kk    410           // ceil(0.8*512)
#define NKk   (Bg*Kk)       // 52480
#define SLOPE 0.2f

typedef float f2v __attribute__((ext_vector_type(2)));

// ---- LDS layout (bytes) inside smem[131072]; regions reused per phase ----
// Phase A:  cnt@0 cur@2048 deg@4096 dis@6144            (freed before B)
// Phase B:  agg float[512*64] @0 (full 128KB)
// Phase C+: keys@0(4K) mapL@4096(2K) rcnt@6144(2K,live thru E) rcur@8192(2K)
//           icol u16@10240(16K) ival f32@26624(32K) perm u16@59392(1K)
//           e1@60416(2K) e2@62464(2K) ws@64512(64) bufE@64576(8*416*4)
#define OFF_CNT    0
#define OFF_CUR    2048
#define OFF_DEG    4096
#define OFF_DIS    6144
#define OFF_AGG    0
#define OFF_KEYS   0
#define OFF_MAPL   4096
#define OFF_RCNT   6144
#define OFF_RCUR   8192
#define OFF_ICOL   10240
#define OFF_IVAL   26624
#define OFF_PERML  59392
#define OFF_E1     60416
#define OFF_E2     62464
#define OFF_WS     64512
#define OFF_BUF    64576   // + 13312 = 77888 < 131072

// ---------- LDS exclusive scan over 512 ints, 512 threads ----------
__device__ __forceinline__ void scan512(int* buf, int* ws) {
  int t = threadIdx.x, lane = t & 63, w = t >> 6;
  int v = buf[t];
  int s = v;
  #pragma unroll
  for (int d = 1; d < 64; d <<= 1) { int u = __shfl_up(s, d, 64); if (lane >= d) s += u; }
  if (lane == 63) ws[w] = s;
  __syncthreads();
  if (t < 8) {
    int u = ws[t];
    #pragma unroll
    for (int d = 1; d < 8; d <<= 1) { int u2 = __shfl_up(u, d, 64); if (t >= d) u += u2; }
    ws[t] = u;
  }
  __syncthreads();
  int excl = s - v + (w ? ws[w - 1] : 0);
  buf[t] = excl;
  __syncthreads();
}

__global__ __launch_bounds__(512, 1) void k_fused(
    const float* __restrict__ x, const int* __restrict__ row, const int* __restrict__ col,
    const float* __restrict__ attr, const float* __restrict__ att,
    uint32_t* __restrict__ epack, float* __restrict__ ecoef, float* __restrict__ scoreG,
    float* __restrict__ o_xpool, float* __restrict__ o_nrow, float* __restrict__ o_ncol,
    float* __restrict__ o_attn, float* __restrict__ o_batch) {
  static __shared__ __align__(16) char smem[131072];
  int g = blockIdx.x, t = threadIdx.x, base = g * NPG;
  int lane = t & 63;
  int w = __builtin_amdgcn_readfirstlane(t >> 6);   // wave id, provably uniform
  const int*   rowg  = row  + g * EPG;
  const int*   colg  = col  + g * EPG;
  const float* attrg = attr + g * EPG;
  int* wsS = (int*)(smem + OFF_WS);

  // ================= A: deg/dis + src-sorted packed edge list =================
  {
    int* cnt = (int*)(smem + OFF_CNT);
    int* cur = (int*)(smem + OFF_CUR);
    float* deg = (float*)(smem + OFF_DEG);
    float* dis = (float*)(smem + OFF_DIS);
    cnt[t] = 0; deg[t] = 0.f;
    __syncthreads();
    for (int i = t; i < EPG; i += 512) {
      int s = rowg[i] - base;
      atomicAdd(&cnt[s], 1);
      atomicAdd(&deg[s], attrg[i]);
    }
    __syncthreads();
    { float d = deg[t]; dis[t] = (d > 0.f) ? rsqrtf(fmaxf(d, 1e-12f)) : 0.f; }
    scan512(cnt, wsS);                 // cnt := exclusive offsets keyed by src
    cur[t] = cnt[t];
    __syncthreads();
    for (int i = t; i < EPG; i += 512) {
      int s = rowg[i] - base, c = colg[i] - base;
      int slot = atomicAdd(&cur[s], 1);
      epack[g * EPG + slot] = ((uint32_t)s << 16) | (uint32_t)c;
      ecoef[g * EPG + slot] = dis[s] * attrg[i] * dis[c];
    }
    __syncthreads();                   // epack/ecoef visible; A LDS freed
  }

  // ================= B: score via src-sorted scatter, 2 channel passes =======
  {
    float* agg = (float*)(smem + OFF_AGG);     // [512][64]
    for (int pass = 0; pass < 2; ++pass) {
      for (int i = t; i < NPG * 64; i += 512) agg[i] = 0.f;
      __syncthreads();
      const uint32_t* ep = epack + g * EPG + w * 1024;
      const float*    ec = ecoef + g * EPG + w * 1024;
      for (int eb = 0; eb < 1024; eb += 64) {
        uint32_t pk = ep[eb + lane];           // 64 edges, coalesced
        float    cf = ec[eb + lane];
        #pragma unroll                          // full unroll -> v_readlane bcast
        for (int j = 0; j < 64; ++j) {
          uint32_t pj = (uint32_t)__shfl((int)pk, j, 64);
          float    cj = __shfl(cf, j, 64);
          int sj = pj >> 16, dj = pj & 0xffff;
          float xv = x[(size_t)(base + sj) * Cc + pass * 64 + lane];
          atomicAdd(&agg[(dj << 6) + lane], cj * xv);   // ds_add, no read-back
        }
      }
      __syncthreads();
      for (int r = w; r < NPG; r += 8) {
        float xv = x[(size_t)(base + r) * Cc + pass * 64 + lane];
        float v = fabsf(xv - agg[(r << 6) + lane]);
        #pragma unroll
        for (int d = 32; d; d >>= 1) v += __shfl_xor(v, d, 64);
        if (lane == 0) {
          if (pass == 0) scoreG[base + r] = v;
          else           scoreG[base + r] += v;
        }
      }
      __syncthreads();                 // agg consumed before next zero
    }
  }

  // ================= C: stable top-k bitonic + induced CSR (all LDS) =========
  unsigned long long* keys = (unsigned long long*)(smem + OFF_KEYS);
  int* mapL = (int*)(smem + OFF_MAPL);
  int* rcnt = (int*)(smem + OFF_RCNT);          // becomes roffs, live thru E
  int* rcur = (int*)(smem + OFF_RCUR);
  uint16_t* icolL = (uint16_t*)(smem + OFF_ICOL);
  float* ivalL = (float*)(smem + OFF_IVAL);
  uint16_t* permL = (uint16_t*)(smem + OFF_PERML);
  {
    float sc = scoreG[base + t];
    unsigned u = __float_as_uint(sc);
    unsigned ord = (u & 0x80000000u) ? ~u : (u | 0x80000000u);
    keys[t] = ((unsigned long long)(~ord) << 32) | (unsigned)t;
  }
  for (int k2 = 2; k2 <= 512; k2 <<= 1) {
    for (int j2 = k2 >> 1; j2 > 0; j2 >>= 1) {
      __syncthreads();
      int ixj = t ^ j2;
      if (ixj > t) {
        unsigned long long a = keys[t], b = keys[ixj];
        bool up = ((t & k2) == 0);
        if ((a > b) == up) { keys[t] = b; keys[ixj] = a; }
      }
    }
  }
  __syncthreads();
  {
    int local = (int)(keys[t] & 0xFFFFFFFFu);
    mapL[local] = (t < Kk) ? t : -1;
    if (t < Kk) { permL[t] = (uint16_t)local; o_batch[g * Kk + t] = (float)g; }
    rcnt[t] = 0;
  }
  __syncthreads();
  for (int i = t; i < EPG; i += 512) {
    int mr = mapL[rowg[i] - base], mc = mapL[colg[i] - base];
    if (mr >= 0 && mc >= 0) atomicAdd(&rcnt[mr], 1);
  }
  __syncthreads();
  scan512(rcnt, wsS);
  rcur[t] = rcnt[t];
  __syncthreads();
  for (int i = t; i < EPG; i += 512) {
    int mr = mapL[rowg[i] - base], mc = mapL[colg[i] - base];
    if (mr >= 0 && mc >= 0) {
      int slot = atomicAdd(&rcur[mr], 1);
      icolL[slot] = (uint16_t)mc;
      ivalL[slot] = attrg[i];
    }
  }
  __syncthreads();

  // ================= D: x_pool gather + e1/e2 GEMV ============================
  float* e1L = (float*)(smem + OFF_E1);
  float* e2L = (float*)(smem + OFF_E2);
  {
    const float2* att2 = (const float2*)att;
    float2 a1v = att2[lane], a2v = att2[64 + lane];
    const float2* x2 = (const float2*)x;
    for (int j = w; j < Kk; j += 8) {
      int lsrc = permL[j];
      float2 xv = x2[(size_t)(base + lsrc) * 64 + lane];
      ((float2*)o_xpool)[(size_t)(g * Kk + j) * 64 + lane] = xv;
      float s1 = xv.x * a1v.x + xv.y * a1v.y;
      float s2 = xv.x * a2v.x + xv.y * a2v.y;
      #pragma unroll
      for (int d = 32; d; d >>= 1) { s1 += __shfl_xor(s1, d, 64); s2 += __shfl_xor(s2, d, 64); }
      if (lane == 0) { e1L[j] = s1; e2L[j] = s2; }
    }
  }
  __syncthreads();

  // ================= E: W build + softmax + attn/new_edge writes ==============
  {
    float* bw = (float*)(smem + OFF_BUF) + w * 416;   // per-wave row buffer
    for (int r = w; r < Kk; r += 8) {
      float ev = e1L[r];
      for (int j = lane; j < Kk; j += 64) {
        float v = ev + e2L[j];
        bw[j] = (v > 0.f) ? v : SLOPE * v;
      }
      int t0 = rcnt[r], t1 = rcnt[r + 1];
      for (int p = t0 + lane; p < t1; p += 64)
        atomicAdd(&bw[icolL[p]], ivalL[p]);           // LAMB = 1.0
      float m = -1e30f;
      for (int j = lane; j < Kk; j += 64) m = fmaxf(m, bw[j]);
      #pragma unroll
      for (int d = 32; d; d >>= 1) m = fmaxf(m, __shfl_xor(m, d, 64));
      float s = 0.f;
      for (int j = lane; j < Kk; j += 64) {
        float ex = __expf(bw[j] - m);
        bw[j] = ex;
        s += ex;
      }
      #pragma unroll
      for (int d = 32; d; d >>= 1) s += __shfl_xor(s, d, 64);
      float inv = 1.f / s;
      int rowid = g * Kk + r;
      size_t fb = (size_t)rowid * Kk;
      f2v* ap = (f2v*)(o_attn + fb);
      f2v* nr = (f2v*)(o_nrow + fb);
      f2v* nc = (f2v*)(o_ncol + fb);
      float frow = (float)rowid, cbase = (float)(g * Kk);
      for (int p = lane; p < Kk / 2; p += 64) {
        int j = 2 * p;
        f2v av; av.x = bw[j] * inv; av.y = bw[j + 1] * inv;
        f2v rv; rv.x = frow; rv.y = frow;
        f2v cv; cv.x = cbase + j; cv.y = cbase + j + 1;
        __builtin_nontemporal_store(av, ap + p);
        __builtin_nontemporal_store(rv, nr + p);
        __builtin_nontemporal_store(cv, nc + p);
      }
    }
  }
}

// ---------------- host launch ----------------
extern "C" void kernel_launch(void* const* d_in, const int* in_sizes, int n_in,
                              void* d_out, int out_size, void* d_ws, size_t ws_size,
                              hipStream_t stream) {
  const float* x    = (const float*)d_in[0];
  const int*   row  = (const int*)d_in[1];
  const int*   col  = row + Ee;
  const float* attr = (const float*)d_in[2];
  const float* att  = (const float*)d_in[4];

  char* ws = (char*)d_ws;
  size_t off = 0;
  auto alloc = [&](size_t bytes) { char* p = ws + off; off = (off + bytes + 255) & ~(size_t)255; return p; };
  uint32_t* epack  = (uint32_t*)alloc((size_t)Ee * 4);
  float*    ecoef  = (float*)   alloc((size_t)Ee * 4);
  float*    scoreG = (float*)   alloc((size_t)Nn * 4);

  // output layout: x_pool | new_row | new_col | attn | batch_pool (all fp32)
  float* out      = (float*)d_out;
  float* o_xpool  = out;
  float* o_nrow   = o_xpool + (size_t)NKk * Cc;
  float* o_ncol   = o_nrow + (size_t)NKk * Kk;
  float* o_attn   = o_ncol + (size_t)NKk * Kk;
  float* o_batch  = o_attn + (size_t)NKk * Kk;

  k_fused<<<Bg, 512, 0, stream>>>(x, row, col, attr, att, epack, ecoef, scoreG,
                                  o_xpool, o_nrow, o_ncol, o_attn, o_batch);
}

// Round 8
// 223.225 us; speedup vs baseline: 7.2941x; 7.2941x over previous
//
#include <hip/hip_runtime.h>
#include <stdint.h>

// Problem constants (from reference setup_inputs)
#define Bg    128
#define NPG   512
#define Cc    128
#define EPG   8192
#define Nn    (Bg*NPG)      // 65536
#define Ee    (Bg*EPG)      // 1048576
#define Kk    410           // ceil(0.8*512)
#define NKk   (Bg*Kk)       // 52480
#define ROFFS_STRIDE 411    // per-graph row-offset stride (410 rows + end sentinel)
#define SLOPE 0.2f

typedef float f2v __attribute__((ext_vector_type(2)));

// ---------- LDS exclusive scan over 512 ints, 512 threads ----------
__device__ __forceinline__ void scan512(int* buf, int* ws) {
  int t = threadIdx.x, lane = t & 63, w = t >> 6;
  int v = buf[t];
  int s = v;
  #pragma unroll
  for (int d = 1; d < 64; d <<= 1) { int u = __shfl_up(s, d, 64); if (lane >= d) s += u; }
  if (lane == 63) ws[w] = s;
  __syncthreads();
  if (t < 8) {
    int u = ws[t];
    #pragma unroll
    for (int d = 1; d < 8; d <<= 1) { int u2 = __shfl_up(u, d, 64); if (t >= d) u += u2; }
    ws[t] = u;
  }
  __syncthreads();
  int excl = s - v + (w ? ws[w - 1] : 0);
  buf[t] = excl;
  __syncthreads();
}

// ---------- K1: per-graph fused {deg, dis, in-count, scan, dst-CSR scatter} ----------
__global__ __launch_bounds__(512) void k_build_csr(const int* __restrict__ row,
                                                   const int* __restrict__ col,
                                                   const float* __restrict__ attr,
                                                   int* __restrict__ offs,
                                                   int* __restrict__ csr_src,
                                                   float* __restrict__ csr_coef) {
  __shared__ int cnt[512];
  __shared__ int cur[512];
  __shared__ float degL[512];
  __shared__ float disL[512];
  __shared__ int ws[8];
  int g = blockIdx.x, t = threadIdx.x, base = g * NPG;
  const int*   rowg  = row  + g * EPG;
  const int*   colg  = col  + g * EPG;
  const float* attrg = attr + g * EPG;
  cnt[t] = 0; degL[t] = 0.f;
  __syncthreads();
  for (int i = t; i < EPG; i += 512) {
    atomicAdd(&cnt[colg[i] - base], 1);
    atomicAdd(&degL[rowg[i] - base], attrg[i]);
  }
  __syncthreads();
  float d = degL[t];
  disL[t] = (d > 0.f) ? rsqrtf(fmaxf(d, 1e-12f)) : 0.f;
  scan512(cnt, ws);
  offs[base + t] = g * EPG + cnt[t];
  if (t == 0) offs[base + NPG] = g * EPG + EPG;
  cur[t] = cnt[t];
  __syncthreads();
  for (int i = t; i < EPG; i += 512) {
    int s = rowg[i] - base, c = colg[i] - base;
    int slot = atomicAdd(&cur[c], 1);
    csr_src[g * EPG + slot]  = rowg[i];                          // global src node id
    csr_coef[g * EPG + slot] = disL[s] * attrg[i] * disL[c];
  }
}

// ---------- K2: score, half-wave float4 gather ----------
// one wave per node; lanes 0-31 process even CSR slots, lanes 32-63 odd;
// each lane covers 4 channels (float4, 32 lanes x 16B = 512B row).
// Halves the serial edge-loop depth vs the 2ch/lane version; same fp32
// partial-sum structure (even-chain + odd-chain) as round 3.
__global__ __launch_bounds__(256) void k_score(const float* __restrict__ x,
                                               const int* __restrict__ offs,
                                               const int* __restrict__ csr_src,
                                               const float* __restrict__ csr_coef,
                                               float* __restrict__ score) {
  int lane = threadIdx.x & 63;
  int node = blockIdx.x * 4 + (threadIdx.x >> 6);
  int c4 = lane & 31, eh = lane >> 5;
  const float4* xp4 = (const float4*)x;   // x row = 32 float4
  float4 xv = xp4[(size_t)node * 32 + c4];
  int s0 = offs[node], s1 = offs[node + 1];
  float a0 = 0.f, a1 = 0.f, a2 = 0.f, a3 = 0.f;
  for (int s = s0 + eh; s < s1; s += 2) {
    int i = csr_src[s];
    float cf = csr_coef[s];
    float4 v = xp4[(size_t)i * 32 + c4];
    a0 += cf * v.x; a1 += cf * v.y; a2 += cf * v.z; a3 += cf * v.w;
  }
  // merge even/odd halves (lane l <-> l^32)
  a0 += __shfl_xor(a0, 32, 64);
  a1 += __shfl_xor(a1, 32, 64);
  a2 += __shfl_xor(a2, 32, 64);
  a3 += __shfl_xor(a3, 32, 64);
  float v = fabsf(xv.x - a0) + fabsf(xv.y - a1) + fabsf(xv.z - a2) + fabsf(xv.w - a3);
  #pragma unroll
  for (int d = 16; d; d >>= 1) v += __shfl_xor(v, d, 64);
  if (lane == 0) score[node] = v;
}

// ---------- K3: per-graph fused {stable top-k sort, induced CSR, x_pool+e1/e2} ----------
__global__ __launch_bounds__(512) void k_topk_induced_feat(
    const float* __restrict__ score,
    const int* __restrict__ row, const int* __restrict__ col,
    const float* __restrict__ attr, const float* __restrict__ x,
    const float* __restrict__ att,
    float* __restrict__ batch_out, int* __restrict__ roffs,
    int* __restrict__ icol, float* __restrict__ ival,
    float* __restrict__ e1, float* __restrict__ e2,
    float* __restrict__ xpool) {
  __shared__ unsigned long long keys[512];
  __shared__ int mapL[512];
  __shared__ int rcnt[512];
  __shared__ int rcur[512];
  __shared__ uint16_t permL[512];
  __shared__ int ws[8];
  int g = blockIdx.x, t = threadIdx.x, base = g * NPG;
  // stable descending argsort via 64-bit keys
  float sc = score[base + t];
  unsigned u = __float_as_uint(sc);
  unsigned ord = (u & 0x80000000u) ? ~u : (u | 0x80000000u);
  keys[t] = ((unsigned long long)(~ord) << 32) | (unsigned)t;
  for (int k2 = 2; k2 <= 512; k2 <<= 1) {
    for (int j2 = k2 >> 1; j2 > 0; j2 >>= 1) {
      __syncthreads();
      int ixj = t ^ j2;
      if (ixj > t) {
        unsigned long long a = keys[t], b = keys[ixj];
        bool up = ((t & k2) == 0);
        if ((a > b) == up) { keys[t] = b; keys[ixj] = a; }
      }
    }
  }
  __syncthreads();
  int local = (int)(keys[t] & 0xFFFFFFFFu);
  mapL[local] = (t < Kk) ? t : -1;
  if (t < Kk) {
    permL[t] = (uint16_t)local;
    batch_out[g * Kk + t] = (float)g;
  }
  rcnt[t] = 0;
  __syncthreads();
  const int*   rowg  = row  + g * EPG;
  const int*   colg  = col  + g * EPG;
  const float* attrg = attr + g * EPG;
  for (int i = t; i < EPG; i += 512) {
    int mr = mapL[rowg[i] - base], mc = mapL[colg[i] - base];
    if (mr >= 0 && mc >= 0) atomicAdd(&rcnt[mr], 1);
  }
  __syncthreads();
  scan512(rcnt, ws);
  if (t <= Kk) roffs[g * ROFFS_STRIDE + t] = g * EPG + rcnt[t];
  rcur[t] = rcnt[t];
  __syncthreads();
  for (int i = t; i < EPG; i += 512) {
    int mr = mapL[rowg[i] - base], mc = mapL[colg[i] - base];
    if (mr >= 0 && mc >= 0) {
      int slot = atomicAdd(&rcur[mr], 1);
      icol[g * EPG + slot] = mc;
      ival[g * EPG + slot] = attrg[i];
    }
  }
  // ---- feat: x_pool gather + e1/e2 GEMV (permL already barrier-visible) ----
  int lane = t & 63, w = t >> 6;
  const float2* att2 = (const float2*)att;
  float2 a1v = att2[lane], a2v = att2[64 + lane];
  const float2* x2 = (const float2*)x;
  for (int j = w; j < Kk; j += 8) {
    int lsrc = permL[j];
    float2 xv = x2[(size_t)(base + lsrc) * 64 + lane];
    ((float2*)xpool)[(size_t)(g * Kk + j) * 64 + lane] = xv;
    float s1 = xv.x * a1v.x + xv.y * a1v.y;
    float s2 = xv.x * a2v.x + xv.y * a2v.y;
    #pragma unroll
    for (int d = 32; d; d >>= 1) { s1 += __shfl_xor(s1, d, 64); s2 += __shfl_xor(s2, d, 64); }
    if (lane == 0) { e1[g * Kk + j] = s1; e2[g * Kk + j] = s2; }
  }
}

// ---------- K4: fused W build + softmax + attn/new_row/new_col writes ----------
__global__ __launch_bounds__(256) void k_softmax(const float* __restrict__ e1,
                                                 const float* __restrict__ e2,
                                                 const int* __restrict__ roffs,
                                                 const int* __restrict__ icol,
                                                 const float* __restrict__ ival,
                                                 float* __restrict__ attn,
                                                 float* __restrict__ nrow,
                                                 float* __restrict__ ncol) {
  __shared__ float buf[4][412];
  int lane = threadIdx.x & 63, w = threadIdx.x >> 6;
  int rowid = blockIdx.x * 4 + w;
  int b = rowid / Kk;
  int r = rowid - b * Kk;
  float ev = e1[rowid];
  const float* e2g = e2 + b * Kk;
  for (int j = lane; j < Kk; j += 64) {
    float v = ev + e2g[j];
    buf[w][j] = (v > 0.f) ? v : SLOPE * v;
  }
  __syncthreads();
  int t0 = roffs[b * ROFFS_STRIDE + r], t1 = roffs[b * ROFFS_STRIDE + r + 1];
  for (int p = t0 + lane; p < t1; p += 64)
    atomicAdd(&buf[w][icol[p]], ival[p]);          // LAMB = 1.0
  __syncthreads();
  float m = -1e30f;
  for (int j = lane; j < Kk; j += 64) m = fmaxf(m, buf[w][j]);
  #pragma unroll
  for (int d = 32; d; d >>= 1) m = fmaxf(m, __shfl_xor(m, d, 64));
  float s = 0.f;
  for (int j = lane; j < Kk; j += 64) {
    float ex = __expf(buf[w][j] - m);
    buf[w][j] = ex;
    s += ex;
  }
  #pragma unroll
  for (int d = 32; d; d >>= 1) s += __shfl_xor(s, d, 64);
  float inv = 1.f / s;
  size_t fb = (size_t)rowid * Kk;
  f2v* ap = (f2v*)(attn + fb);
  f2v* nr = (f2v*)(nrow + fb);
  f2v* nc = (f2v*)(ncol + fb);
  float frow  = (float)rowid;
  float cbase = (float)(b * Kk);
  for (int p = lane; p < Kk / 2; p += 64) {
    int j = 2 * p;
    f2v av; av.x = buf[w][j] * inv; av.y = buf[w][j + 1] * inv;
    f2v rv; rv.x = frow; rv.y = frow;
    f2v cv; cv.x = cbase + j; cv.y = cbase + j + 1;
    __builtin_nontemporal_store(av, ap + p);
    __builtin_nontemporal_store(rv, nr + p);
    __builtin_nontemporal_store(cv, nc + p);
  }
}

// ---------------- host launch ----------------
extern "C" void kernel_launch(void* const* d_in, const int* in_sizes, int n_in,
                              void* d_out, int out_size, void* d_ws, size_t ws_size,
                              hipStream_t stream) {
  const float* x    = (const float*)d_in[0];
  const int*   row  = (const int*)d_in[1];
  const int*   col  = row + Ee;
  const float* attr = (const float*)d_in[2];
  const float* att  = (const float*)d_in[4];

  char* ws = (char*)d_ws;
  size_t off = 0;
  auto alloc = [&](size_t bytes) { char* p = ws + off; off = (off + bytes + 255) & ~(size_t)255; return p; };
  int*   offs     = (int*)  alloc((size_t)(Nn + 1) * 4);
  int*   csr_src  = (int*)  alloc((size_t)Ee * 4);
  float* csr_coef = (float*)alloc((size_t)Ee * 4);
  float* score    = (float*)alloc((size_t)Nn * 4);
  int*   roffs    = (int*)  alloc((size_t)Bg * ROFFS_STRIDE * 4);
  int*   icol     = (int*)  alloc((size_t)Ee * 4);
  float* ival     = (float*)alloc((size_t)Ee * 4);
  float* e1       = (float*)alloc((size_t)NKk * 4);
  float* e2       = (float*)alloc((size_t)NKk * 4);

  // output layout: x_pool | new_row | new_col | attn | batch_pool (all fp32)
  float* out      = (float*)d_out;
  float* o_xpool  = out;
  float* o_nrow   = o_xpool + (size_t)NKk * Cc;
  float* o_ncol   = o_nrow + (size_t)NKk * Kk;
  float* o_attn   = o_ncol + (size_t)NKk * Kk;
  float* o_batch  = o_attn + (size_t)NKk * Kk;

  k_build_csr          <<<Bg,      512, 0, stream>>>(row, col, attr, offs, csr_src, csr_coef);
  k_score              <<<Nn / 4,  256, 0, stream>>>(x, offs, csr_src, csr_coef, score);
  k_topk_induced_feat  <<<Bg,      512, 0, stream>>>(score, row, col, attr, x, att,
                                                     o_batch, roffs, icol, ival, e1, e2, o_xpool);
  k_softmax            <<<NKk / 4, 256, 0, stream>>>(e1, e2, roffs, icol, ival, o_attn, o_nrow, o_ncol);
}

// Round 9
// 215.866 us; speedup vs baseline: 7.5428x; 1.0341x over previous
//
#include <hip/hip_runtime.h>
#include <stdint.h>

// Problem constants (from reference setup_inputs)
#define Bg    128
#define NPG   512
#define Cc    128
#define EPG   8192
#define Nn    (Bg*NPG)      // 65536
#define Ee    (Bg*EPG)      // 1048576
#define Kk    410           // ceil(0.8*512)
#define NKk   (Bg*Kk)       // 52480
#define ROFFS_STRIDE 411    // per-graph row-offset stride (410 rows + end sentinel)
#define SLOPE 0.2f

typedef float f2v __attribute__((ext_vector_type(2)));

// ---------- LDS exclusive scan over 512 ints, 512 threads ----------
__device__ __forceinline__ void scan512(int* buf, int* ws) {
  int t = threadIdx.x, lane = t & 63, w = t >> 6;
  int v = buf[t];
  int s = v;
  #pragma unroll
  for (int d = 1; d < 64; d <<= 1) { int u = __shfl_up(s, d, 64); if (lane >= d) s += u; }
  if (lane == 63) ws[w] = s;
  __syncthreads();
  if (t < 8) {
    int u = ws[t];
    #pragma unroll
    for (int d = 1; d < 8; d <<= 1) { int u2 = __shfl_up(u, d, 64); if (t >= d) u += u2; }
    ws[t] = u;
  }
  __syncthreads();
  int excl = s - v + (w ? ws[w - 1] : 0);
  buf[t] = excl;
  __syncthreads();
}

// ---------- K1: per-graph fused {deg, dis, in-count, scan, dst-CSR scatter} ----------
__global__ __launch_bounds__(512) void k_build_csr(const int* __restrict__ row,
                                                   const int* __restrict__ col,
                                                   const float* __restrict__ attr,
                                                   int* __restrict__ offs,
                                                   int* __restrict__ csr_src,
                                                   float* __restrict__ csr_coef) {
  __shared__ int cnt[512];
  __shared__ int cur[512];
  __shared__ float degL[512];
  __shared__ float disL[512];
  __shared__ int ws[8];
  int g = blockIdx.x, t = threadIdx.x, base = g * NPG;
  const int*   rowg  = row  + g * EPG;
  const int*   colg  = col  + g * EPG;
  const float* attrg = attr + g * EPG;
  cnt[t] = 0; degL[t] = 0.f;
  __syncthreads();
  for (int i = t; i < EPG; i += 512) {
    atomicAdd(&cnt[colg[i] - base], 1);
    atomicAdd(&degL[rowg[i] - base], attrg[i]);
  }
  __syncthreads();
  float d = degL[t];
  disL[t] = (d > 0.f) ? rsqrtf(fmaxf(d, 1e-12f)) : 0.f;
  scan512(cnt, ws);
  offs[base + t] = g * EPG + cnt[t];
  if (t == 0) offs[base + NPG] = g * EPG + EPG;
  cur[t] = cnt[t];
  __syncthreads();
  for (int i = t; i < EPG; i += 512) {
    int s = rowg[i] - base, c = colg[i] - base;
    int slot = atomicAdd(&cur[c], 1);
    csr_src[g * EPG + slot]  = rowg[i];                          // global src node id
    csr_coef[g * EPG + slot] = disL[s] * attrg[i] * disL[c];
  }
}

// ---------- K2: score, full-wave float2 gather, 8-way unrolled ----------
// one wave per node, 2 channels per lane (float2, 64 lanes = 512B row).
// 8 independent row-gathers in flight per iteration (R3 had 4); csr_src/coef
// index loads collapse into dwordx4s. Latency/MLP-bound -> more outstanding
// loads is the lever (R5 diag: 36 GB/s HBM, 78% occ, ~10.7 TB/s eff gather).
__global__ __launch_bounds__(256) void k_score(const float* __restrict__ x,
                                               const int* __restrict__ offs,
                                               const int* __restrict__ csr_src,
                                               const float* __restrict__ csr_coef,
                                               float* __restrict__ score) {
  int lane = threadIdx.x & 63;
  int node = blockIdx.x * 4 + (threadIdx.x >> 6);
  const float2* xp = (const float2*)x;
  float2 xv = xp[(size_t)node * 64 + lane];
  int s0 = offs[node], s1 = offs[node + 1];
  float a0 = 0.f, a1 = 0.f, b0 = 0.f, b1 = 0.f;
  float c0 = 0.f, c1 = 0.f, d0 = 0.f, d1 = 0.f;
  int s = s0;
  for (; s + 8 <= s1; s += 8) {
    int   i0 = csr_src[s],    i1 = csr_src[s+1],  i2 = csr_src[s+2],  i3 = csr_src[s+3];
    int   i4 = csr_src[s+4],  i5 = csr_src[s+5],  i6 = csr_src[s+6],  i7 = csr_src[s+7];
    float f0 = csr_coef[s],   f1 = csr_coef[s+1], f2 = csr_coef[s+2], f3 = csr_coef[s+3];
    float f4 = csr_coef[s+4], f5 = csr_coef[s+5], f6 = csr_coef[s+6], f7 = csr_coef[s+7];
    float2 v0 = xp[(size_t)i0 * 64 + lane];
    float2 v1 = xp[(size_t)i1 * 64 + lane];
    float2 v2 = xp[(size_t)i2 * 64 + lane];
    float2 v3 = xp[(size_t)i3 * 64 + lane];
    float2 v4 = xp[(size_t)i4 * 64 + lane];
    float2 v5 = xp[(size_t)i5 * 64 + lane];
    float2 v6 = xp[(size_t)i6 * 64 + lane];
    float2 v7 = xp[(size_t)i7 * 64 + lane];
    a0 += f0 * v0.x; a1 += f0 * v0.y;
    b0 += f1 * v1.x; b1 += f1 * v1.y;
    c0 += f2 * v2.x; c1 += f2 * v2.y;
    d0 += f3 * v3.x; d1 += f3 * v3.y;
    a0 += f4 * v4.x; a1 += f4 * v4.y;
    b0 += f5 * v5.x; b1 += f5 * v5.y;
    c0 += f6 * v6.x; c1 += f6 * v6.y;
    d0 += f7 * v7.x; d1 += f7 * v7.y;
  }
  for (; s + 4 <= s1; s += 4) {
    int   i0 = csr_src[s],   i1 = csr_src[s+1],  i2 = csr_src[s+2],  i3 = csr_src[s+3];
    float f0 = csr_coef[s],  f1 = csr_coef[s+1], f2 = csr_coef[s+2], f3 = csr_coef[s+3];
    float2 v0 = xp[(size_t)i0 * 64 + lane];
    float2 v1 = xp[(size_t)i1 * 64 + lane];
    float2 v2 = xp[(size_t)i2 * 64 + lane];
    float2 v3 = xp[(size_t)i3 * 64 + lane];
    a0 += f0 * v0.x; a1 += f0 * v0.y;
    b0 += f1 * v1.x; b1 += f1 * v1.y;
    c0 += f2 * v2.x; c1 += f2 * v2.y;
    d0 += f3 * v3.x; d1 += f3 * v3.y;
  }
  for (; s < s1; ++s) {
    int i0 = csr_src[s]; float f0 = csr_coef[s];
    float2 v0 = xp[(size_t)i0 * 64 + lane];
    a0 += f0 * v0.x; a1 += f0 * v0.y;
  }
  float v = fabsf(xv.x - a0 - b0 - c0 - d0) + fabsf(xv.y - a1 - b1 - c1 - d1);
  #pragma unroll
  for (int d = 32; d; d >>= 1) v += __shfl_xor(v, d, 64);
  if (lane == 0) score[node] = v;
}

// ---------- K3: per-graph fused {stable top-k sort, induced CSR, x_pool+e1/e2} ----------
__global__ __launch_bounds__(512) void k_topk_induced_feat(
    const float* __restrict__ score,
    const int* __restrict__ row, const int* __restrict__ col,
    const float* __restrict__ attr, const float* __restrict__ x,
    const float* __restrict__ att,
    float* __restrict__ batch_out, int* __restrict__ roffs,
    int* __restrict__ icol, float* __restrict__ ival,
    float* __restrict__ e1, float* __restrict__ e2,
    float* __restrict__ xpool) {
  __shared__ unsigned long long keys[512];
  __shared__ int mapL[512];
  __shared__ int rcnt[512];
  __shared__ int rcur[512];
  __shared__ uint16_t permL[512];
  __shared__ int ws[8];
  int g = blockIdx.x, t = threadIdx.x, base = g * NPG;
  float sc = score[base + t];
  unsigned u = __float_as_uint(sc);
  unsigned ord = (u & 0x80000000u) ? ~u : (u | 0x80000000u);
  keys[t] = ((unsigned long long)(~ord) << 32) | (unsigned)t;
  for (int k2 = 2; k2 <= 512; k2 <<= 1) {
    for (int j2 = k2 >> 1; j2 > 0; j2 >>= 1) {
      __syncthreads();
      int ixj = t ^ j2;
      if (ixj > t) {
        unsigned long long a = keys[t], b = keys[ixj];
        bool up = ((t & k2) == 0);
        if ((a > b) == up) { keys[t] = b; keys[ixj] = a; }
      }
    }
  }
  __syncthreads();
  int local = (int)(keys[t] & 0xFFFFFFFFu);
  mapL[local] = (t < Kk) ? t : -1;
  if (t < Kk) {
    permL[t] = (uint16_t)local;
    batch_out[g * Kk + t] = (float)g;
  }
  rcnt[t] = 0;
  __syncthreads();
  const int*   rowg  = row  + g * EPG;
  const int*   colg  = col  + g * EPG;
  const float* attrg = attr + g * EPG;
  for (int i = t; i < EPG; i += 512) {
    int mr = mapL[rowg[i] - base], mc = mapL[colg[i] - base];
    if (mr >= 0 && mc >= 0) atomicAdd(&rcnt[mr], 1);
  }
  __syncthreads();
  scan512(rcnt, ws);
  if (t <= Kk) roffs[g * ROFFS_STRIDE + t] = g * EPG + rcnt[t];
  rcur[t] = rcnt[t];
  __syncthreads();
  for (int i = t; i < EPG; i += 512) {
    int mr = mapL[rowg[i] - base], mc = mapL[colg[i] - base];
    if (mr >= 0 && mc >= 0) {
      int slot = atomicAdd(&rcur[mr], 1);
      icol[g * EPG + slot] = mc;
      ival[g * EPG + slot] = attrg[i];
    }
  }
  // ---- feat: x_pool gather + e1/e2 GEMV (permL already barrier-visible) ----
  int lane = t & 63, w = t >> 6;
  const float2* att2 = (const float2*)att;
  float2 a1v = att2[lane], a2v = att2[64 + lane];
  const float2* x2 = (const float2*)x;
  for (int j = w; j < Kk; j += 8) {
    int lsrc = permL[j];
    float2 xv = x2[(size_t)(base + lsrc) * 64 + lane];
    ((float2*)xpool)[(size_t)(g * Kk + j) * 64 + lane] = xv;
    float s1 = xv.x * a1v.x + xv.y * a1v.y;
    float s2 = xv.x * a2v.x + xv.y * a2v.y;
    #pragma unroll
    for (int d = 32; d; d >>= 1) { s1 += __shfl_xor(s1, d, 64); s2 += __shfl_xor(s2, d, 64); }
    if (lane == 0) { e1[g * Kk + j] = s1; e2[g * Kk + j] = s2; }
  }
}

// ---------- K4: fused W build + softmax + attn/new_row/new_col writes ----------
__global__ __launch_bounds__(256) void k_softmax(const float* __restrict__ e1,
                                                 const float* __restrict__ e2,
                                                 const int* __restrict__ roffs,
                                                 const int* __restrict__ icol,
                                                 const float* __restrict__ ival,
                                                 float* __restrict__ attn,
                                                 float* __restrict__ nrow,
                                                 float* __restrict__ ncol) {
  __shared__ float buf[4][412];
  int lane = threadIdx.x & 63, w = threadIdx.x >> 6;
  int rowid = blockIdx.x * 4 + w;
  int b = rowid / Kk;
  int r = rowid - b * Kk;
  float ev = e1[rowid];
  const float* e2g = e2 + b * Kk;
  for (int j = lane; j < Kk; j += 64) {
    float v = ev + e2g[j];
    buf[w][j] = (v > 0.f) ? v : SLOPE * v;
  }
  __syncthreads();
  int t0 = roffs[b * ROFFS_STRIDE + r], t1 = roffs[b * ROFFS_STRIDE + r + 1];
  for (int p = t0 + lane; p < t1; p += 64)
    atomicAdd(&buf[w][icol[p]], ival[p]);          // LAMB = 1.0
  __syncthreads();
  float m = -1e30f;
  for (int j = lane; j < Kk; j += 64) m = fmaxf(m, buf[w][j]);
  #pragma unroll
  for (int d = 32; d; d >>= 1) m = fmaxf(m, __shfl_xor(m, d, 64));
  float s = 0.f;
  for (int j = lane; j < Kk; j += 64) {
    float ex = __expf(buf[w][j] - m);
    buf[w][j] = ex;
    s += ex;
  }
  #pragma unroll
  for (int d = 32; d; d >>= 1) s += __shfl_xor(s, d, 64);
  float inv = 1.f / s;
  size_t fb = (size_t)rowid * Kk;
  f2v* ap = (f2v*)(attn + fb);
  f2v* nr = (f2v*)(nrow + fb);
  f2v* nc = (f2v*)(ncol + fb);
  float frow  = (float)rowid;
  float cbase = (float)(b * Kk);
  for (int p = lane; p < Kk / 2; p += 64) {
    int j = 2 * p;
    f2v av; av.x = buf[w][j] * inv; av.y = buf[w][j + 1] * inv;
    f2v rv; rv.x = frow; rv.y = frow;
    f2v cv; cv.x = cbase + j; cv.y = cbase + j + 1;
    __builtin_nontemporal_store(av, ap + p);
    __builtin_nontemporal_store(rv, nr + p);
    __builtin_nontemporal_store(cv, nc + p);
  }
}

// ---------------- host launch ----------------
extern "C" void kernel_launch(void* const* d_in, const int* in_sizes, int n_in,
                              void* d_out, int out_size, void* d_ws, size_t ws_size,
                              hipStream_t stream) {
  const float* x    = (const float*)d_in[0];
  const int*   row  = (const int*)d_in[1];
  const int*   col  = row + Ee;
  const float* attr = (const float*)d_in[2];
  const float* att  = (const float*)d_in[4];

  char* ws = (char*)d_ws;
  size_t off = 0;
  auto alloc = [&](size_t bytes) { char* p = ws + off; off = (off + bytes + 255) & ~(size_t)255; return p; };
  int*   offs     = (int*)  alloc((size_t)(Nn + 1) * 4);
  int*   csr_src  = (int*)  alloc((size_t)Ee * 4);
  float* csr_coef = (float*)alloc((size_t)Ee * 4);
  float* score    = (float*)alloc((size_t)Nn * 4);
  int*   roffs    = (int*)  alloc((size_t)Bg * ROFFS_STRIDE * 4);
  int*   icol     = (int*)  alloc((size_t)Ee * 4);
  float* ival     = (float*)alloc((size_t)Ee * 4);
  float* e1       = (float*)alloc((size_t)NKk * 4);
  float* e2       = (float*)alloc((size_t)NKk * 4);

  // output layout: x_pool | new_row | new_col | attn | batch_pool (all fp32)
  float* out      = (float*)d_out;
  float* o_xpool  = out;
  float* o_nrow   = o_xpool + (size_t)NKk * Cc;
  float* o_ncol   = o_nrow + (size_t)NKk * Kk;
  float* o_attn   = o_ncol + (size_t)NKk * Kk;
  float* o_batch  = o_attn + (size_t)NKk * Kk;

  k_build_csr          <<<Bg,      512, 0, stream>>>(row, col, attr, offs, csr_src, csr_coef);
  k_score              <<<Nn / 4,  256, 0, stream>>>(x, offs, csr_src, csr_coef, score);
  k_topk_induced_feat  <<<Bg,      512, 0, stream>>>(score, row, col, attr, x, att,
                                                     o_batch, roffs, icol, ival, e1, e2, o_xpool);
  k_softmax            <<<NKk / 4, 256, 0, stream>>>(e1, e2, roffs, icol, ival, o_attn, o_nrow, o_ncol);
}

// Round 10
// 196.296 us; speedup vs baseline: 8.2947x; 1.0997x over previous
//
#include <hip/hip_runtime.h>
#include <stdint.h>

// Problem constants (from reference setup_inputs)
#define Bg    128
#define NPG   512
#define Cc    128
#define EPG   8192
#define Nn    (Bg*NPG)      // 65536
#define Ee    (Bg*EPG)      // 1048576
#define Kk    410           // ceil(0.8*512)
#define NKk   (Bg*Kk)       // 52480
#define ROFFS_STRIDE 411    // per-graph row-offset stride (410 rows + end sentinel)
#define SLOPE 0.2f

typedef float f2v __attribute__((ext_vector_type(2)));

// bf16x2 (packed in uint32) -> float2 : pure bit ops
__device__ __forceinline__ float2 bf2f(uint32_t p) {
  float2 r;
  r.x = __uint_as_float(p << 16);
  r.y = __uint_as_float(p & 0xffff0000u);
  return r;
}
// float2 -> packed bf16x2, round-to-nearest-even
__device__ __forceinline__ uint32_t f2bf(float2 v) {
  uint32_t lo = __float_as_uint(v.x), hi = __float_as_uint(v.y);
  lo = (lo + 0x7fffu + ((lo >> 16) & 1u)) >> 16;
  hi = (hi + 0x7fffu + ((hi >> 16) & 1u)) & 0xffff0000u;
  return hi | lo;
}

// ---------- LDS exclusive scan over 512 ints, 512 threads ----------
__device__ __forceinline__ void scan512(int* buf, int* ws) {
  int t = threadIdx.x, lane = t & 63, w = t >> 6;
  int v = buf[t];
  int s = v;
  #pragma unroll
  for (int d = 1; d < 64; d <<= 1) { int u = __shfl_up(s, d, 64); if (lane >= d) s += u; }
  if (lane == 63) ws[w] = s;
  __syncthreads();
  if (t < 8) {
    int u = ws[t];
    #pragma unroll
    for (int d = 1; d < 8; d <<= 1) { int u2 = __shfl_up(u, d, 64); if (t >= d) u += u2; }
    ws[t] = u;
  }
  __syncthreads();
  int excl = s - v + (w ? ws[w - 1] : 0);
  buf[t] = excl;
  __syncthreads();
}

// ---------- K1: per-graph {deg, dis, in-count, scan, dst-CSR scatter} + bf16 x copy ----------
__global__ __launch_bounds__(512) void k_build_csr(const int* __restrict__ row,
                                                   const int* __restrict__ col,
                                                   const float* __restrict__ attr,
                                                   const float* __restrict__ x,
                                                   int* __restrict__ offs,
                                                   int* __restrict__ csr_src,
                                                   float* __restrict__ csr_coef,
                                                   uint32_t* __restrict__ xh) {
  __shared__ int cnt[512];
  __shared__ int cur[512];
  __shared__ float degL[512];
  __shared__ float disL[512];
  __shared__ int ws[8];
  int g = blockIdx.x, t = threadIdx.x, base = g * NPG;
  const int*   rowg  = row  + g * EPG;
  const int*   colg  = col  + g * EPG;
  const float* attrg = attr + g * EPG;
  cnt[t] = 0; degL[t] = 0.f;
  __syncthreads();
  for (int i = t; i < EPG; i += 512) {
    atomicAdd(&cnt[colg[i] - base], 1);
    atomicAdd(&degL[rowg[i] - base], attrg[i]);
  }
  __syncthreads();
  float d = degL[t];
  disL[t] = (d > 0.f) ? rsqrtf(fmaxf(d, 1e-12f)) : 0.f;
  scan512(cnt, ws);
  offs[base + t] = g * EPG + cnt[t];
  if (t == 0) offs[base + NPG] = g * EPG + EPG;
  cur[t] = cnt[t];
  __syncthreads();
  for (int i = t; i < EPG; i += 512) {
    int s = rowg[i] - base, c = colg[i] - base;
    int slot = atomicAdd(&cur[c], 1);
    csr_src[g * EPG + slot]  = rowg[i];                          // global src node id
    csr_coef[g * EPG + slot] = disL[s] * attrg[i] * disL[c];
  }
  // bf16 copy of this graph's x slice (for k_score's gather)
  const float2* x2g = (const float2*)x + (size_t)base * 64;
  uint32_t*     xhg = xh + (size_t)base * 64;
  for (int i = t; i < NPG * 64; i += 512) xhg[i] = f2bf(x2g[i]);
}

// ---------- K2: score, bf16 gather (half volume), 4-way unrolled ----------
// one wave per node, 2 channels per lane (uint32 = bf16x2, 64 lanes = 256B row).
// Own row read fp32; agg accumulated fp32 from bf16 operands.
__global__ __launch_bounds__(256) void k_score(const float* __restrict__ x,
                                               const uint32_t* __restrict__ xh,
                                               const int* __restrict__ offs,
                                               const int* __restrict__ csr_src,
                                               const float* __restrict__ csr_coef,
                                               float* __restrict__ score) {
  int bb = blockIdx.x;
  int wg = ((bb & 7) << 11) | (bb >> 3);        // XCD-chunked swizzle, bijective
  int lane = threadIdx.x & 63;
  int node = wg * 4 + (threadIdx.x >> 6);
  const float2* xp = (const float2*)x;
  float2 xv = xp[(size_t)node * 64 + lane];
  int s0 = offs[node], s1 = offs[node + 1];
  float a0 = 0.f, a1 = 0.f, b0 = 0.f, b1 = 0.f;
  int s = s0;
  for (; s + 4 <= s1; s += 4) {
    int   i0 = csr_src[s],   i1 = csr_src[s+1],  i2 = csr_src[s+2],  i3 = csr_src[s+3];
    float c0 = csr_coef[s],  c1 = csr_coef[s+1], c2 = csr_coef[s+2], c3 = csr_coef[s+3];
    uint32_t p0 = xh[(size_t)i0 * 64 + lane];
    uint32_t p1 = xh[(size_t)i1 * 64 + lane];
    uint32_t p2 = xh[(size_t)i2 * 64 + lane];
    uint32_t p3 = xh[(size_t)i3 * 64 + lane];
    float2 v0 = bf2f(p0), v1 = bf2f(p1), v2 = bf2f(p2), v3 = bf2f(p3);
    a0 += c0 * v0.x; a1 += c0 * v0.y;
    b0 += c1 * v1.x; b1 += c1 * v1.y;
    a0 += c2 * v2.x; a1 += c2 * v2.y;
    b0 += c3 * v3.x; b1 += c3 * v3.y;
  }
  for (; s < s1; ++s) {
    int i0 = csr_src[s]; float c0 = csr_coef[s];
    float2 v0 = bf2f(xh[(size_t)i0 * 64 + lane]);
    a0 += c0 * v0.x; a1 += c0 * v0.y;
  }
  float v = fabsf(xv.x - a0 - b0) + fabsf(xv.y - a1 - b1);
  #pragma unroll
  for (int d = 32; d; d >>= 1) v += __shfl_xor(v, d, 64);
  if (lane == 0) score[node] = v;
}

// ---------- K3: per-graph fused {stable top-k bitonic sort, perm/batch, induced CSR} ----------
__global__ __launch_bounds__(512) void k_topk_induced(const float* __restrict__ score,
                                                      const int* __restrict__ row,
                                                      const int* __restrict__ col,
                                                      const float* __restrict__ attr,
                                                      int* __restrict__ perm,
                                                      float* __restrict__ batch_out,
                                                      int* __restrict__ roffs,
                                                      int* __restrict__ icol,
                                                      float* __restrict__ ival) {
  __shared__ unsigned long long keys[512];
  __shared__ int mapL[512];
  __shared__ int rcnt[512];
  __shared__ int rcur[512];
  __shared__ int ws[8];
  int g = blockIdx.x, t = threadIdx.x, base = g * NPG;
  float sc = score[base + t];
  unsigned u = __float_as_uint(sc);
  unsigned ord = (u & 0x80000000u) ? ~u : (u | 0x80000000u);
  keys[t] = ((unsigned long long)(~ord) << 32) | (unsigned)t;
  for (int k2 = 2; k2 <= 512; k2 <<= 1) {
    for (int j2 = k2 >> 1; j2 > 0; j2 >>= 1) {
      __syncthreads();
      int ixj = t ^ j2;
      if (ixj > t) {
        unsigned long long a = keys[t], b = keys[ixj];
        bool up = ((t & k2) == 0);
        if ((a > b) == up) { keys[t] = b; keys[ixj] = a; }
      }
    }
  }
  __syncthreads();
  int local = (int)(keys[t] & 0xFFFFFFFFu);
  mapL[local] = (t < Kk) ? t : -1;
  if (t < Kk) {
    perm[g * Kk + t] = base + local;
    batch_out[g * Kk + t] = (float)g;
  }
  rcnt[t] = 0;
  __syncthreads();
  const int*   rowg  = row  + g * EPG;
  const int*   colg  = col  + g * EPG;
  const float* attrg = attr + g * EPG;
  for (int i = t; i < EPG; i += 512) {
    int mr = mapL[rowg[i] - base], mc = mapL[colg[i] - base];
    if (mr >= 0 && mc >= 0) atomicAdd(&rcnt[mr], 1);
  }
  __syncthreads();
  scan512(rcnt, ws);
  if (t <= Kk) roffs[g * ROFFS_STRIDE + t] = g * EPG + rcnt[t];
  rcur[t] = rcnt[t];
  __syncthreads();
  for (int i = t; i < EPG; i += 512) {
    int mr = mapL[rowg[i] - base], mc = mapL[colg[i] - base];
    if (mr >= 0 && mc >= 0) {
      int slot = atomicAdd(&rcur[mr], 1);
      icol[g * EPG + slot] = mc;
      ival[g * EPG + slot] = attrg[i];
    }
  }
}

// ---------- K4: x_pool gather + e1/e2 GEMV (fused), XCD-chunked swizzle ----------
__global__ __launch_bounds__(256) void k_feat(const float* __restrict__ x,
                                              const int* __restrict__ perm,
                                              const float* __restrict__ att,
                                              float* __restrict__ e1,
                                              float* __restrict__ e2,
                                              float* __restrict__ xpool) {
  int bb = blockIdx.x;
  int wg = (bb & 7) * 1640 + (bb >> 3);         // 13120 = 8*1640, bijective
  int lane = threadIdx.x & 63;
  int j = wg * 4 + (threadIdx.x >> 6);
  int gsrc = perm[j];
  float2 xv = ((const float2*)x)[(size_t)gsrc * 64 + lane];
  ((float2*)xpool)[(size_t)j * 64 + lane] = xv;
  float2 a1 = ((const float2*)att)[lane];
  float2 a2 = ((const float2*)(att + Cc))[lane];
  float s1 = xv.x * a1.x + xv.y * a1.y;
  float s2 = xv.x * a2.x + xv.y * a2.y;
  #pragma unroll
  for (int d = 32; d; d >>= 1) { s1 += __shfl_xor(s1, d, 64); s2 += __shfl_xor(s2, d, 64); }
  if (lane == 0) { e1[j] = s1; e2[j] = s2; }
}

// ---------- K5: fused W build + softmax + attn/new_row/new_col writes ----------
__global__ __launch_bounds__(256) void k_softmax(const float* __restrict__ e1,
                                                 const float* __restrict__ e2,
                                                 const int* __restrict__ roffs,
                                                 const int* __restrict__ icol,
                                                 const float* __restrict__ ival,
                                                 float* __restrict__ attn,
                                                 float* __restrict__ nrow,
                                                 float* __restrict__ ncol) {
  __shared__ float buf[4][412];
  int lane = threadIdx.x & 63, w = threadIdx.x >> 6;
  int rowid = blockIdx.x * 4 + w;
  int b = rowid / Kk;
  int r = rowid - b * Kk;
  float ev = e1[rowid];
  const float* e2g = e2 + b * Kk;
  for (int j = lane; j < Kk; j += 64) {
    float v = ev + e2g[j];
    buf[w][j] = (v > 0.f) ? v : SLOPE * v;
  }
  __syncthreads();
  int t0 = roffs[b * ROFFS_STRIDE + r], t1 = roffs[b * ROFFS_STRIDE + r + 1];
  for (int p = t0 + lane; p < t1; p += 64)
    atomicAdd(&buf[w][icol[p]], ival[p]);          // LAMB = 1.0
  __syncthreads();
  float m = -1e30f;
  for (int j = lane; j < Kk; j += 64) m = fmaxf(m, buf[w][j]);
  #pragma unroll
  for (int d = 32; d; d >>= 1) m = fmaxf(m, __shfl_xor(m, d, 64));
  float s = 0.f;
  for (int j = lane; j < Kk; j += 64) {
    float ex = __expf(buf[w][j] - m);
    buf[w][j] = ex;
    s += ex;
  }
  #pragma unroll
  for (int d = 32; d; d >>= 1) s += __shfl_xor(s, d, 64);
  float inv = 1.f / s;
  size_t fb = (size_t)rowid * Kk;
  f2v* ap = (f2v*)(attn + fb);
  f2v* nr = (f2v*)(nrow + fb);
  f2v* nc = (f2v*)(ncol + fb);
  float frow  = (float)rowid;
  float cbase = (float)(b * Kk);
  for (int p = lane; p < Kk / 2; p += 64) {
    int j = 2 * p;
    f2v av; av.x = buf[w][j] * inv; av.y = buf[w][j + 1] * inv;
    f2v rv; rv.x = frow; rv.y = frow;
    f2v cv; cv.x = cbase + j; cv.y = cbase + j + 1;
    __builtin_nontemporal_store(av, ap + p);
    __builtin_nontemporal_store(rv, nr + p);
    __builtin_nontemporal_store(cv, nc + p);
  }
}

// ---------------- host launch ----------------
extern "C" void kernel_launch(void* const* d_in, const int* in_sizes, int n_in,
                              void* d_out, int out_size, void* d_ws, size_t ws_size,
                              hipStream_t stream) {
  const float* x    = (const float*)d_in[0];
  const int*   row  = (const int*)d_in[1];
  const int*   col  = row + Ee;
  const float* attr = (const float*)d_in[2];
  const float* att  = (const float*)d_in[4];

  char* ws = (char*)d_ws;
  size_t off = 0;
  auto alloc = [&](size_t bytes) { char* p = ws + off; off = (off + bytes + 255) & ~(size_t)255; return p; };
  int*      offs     = (int*)     alloc((size_t)(Nn + 1) * 4);
  int*      csr_src  = (int*)     alloc((size_t)Ee * 4);
  float*    csr_coef = (float*)   alloc((size_t)Ee * 4);
  float*    score    = (float*)   alloc((size_t)Nn * 4);
  int*      perm     = (int*)     alloc((size_t)NKk * 4);
  int*      roffs    = (int*)     alloc((size_t)Bg * ROFFS_STRIDE * 4);
  int*      icol     = (int*)     alloc((size_t)Ee * 4);
  float*    ival     = (float*)   alloc((size_t)Ee * 4);
  float*    e1       = (float*)   alloc((size_t)NKk * 4);
  float*    e2       = (float*)   alloc((size_t)NKk * 4);
  uint32_t* xh       = (uint32_t*)alloc((size_t)Nn * 64 * 4);   // bf16x2 packed, 16MB

  // output layout: x_pool | new_row | new_col | attn | batch_pool (all fp32)
  float* out      = (float*)d_out;
  float* o_xpool  = out;
  float* o_nrow   = o_xpool + (size_t)NKk * Cc;
  float* o_ncol   = o_nrow + (size_t)NKk * Kk;
  float* o_attn   = o_ncol + (size_t)NKk * Kk;
  float* o_batch  = o_attn + (size_t)NKk * Kk;

  k_build_csr  <<<Bg,      512, 0, stream>>>(row, col, attr, x, offs, csr_src, csr_coef, xh);
  k_score      <<<Nn / 4,  256, 0, stream>>>(x, xh, offs, csr_src, csr_coef, score);
  k_topk_induced<<<Bg,     512, 0, stream>>>(score, row, col, attr, perm, o_batch, roffs, icol, ival);
  k_feat       <<<NKk / 4, 256, 0, stream>>>(x, perm, att, e1, e2, o_xpool);
  k_softmax    <<<NKk / 4, 256, 0, stream>>>(e1, e2, roffs, icol, ival, o_attn, o_nrow, o_ncol);
}